// Round 8
// baseline (19.321 us; speedup 1.0000x reference)
//
#include <hip/hip_runtime.h>
#include <utility>

// Geometric product in Cl(3,2,1), DIM=64.
// out[n,k] = sum_a sign(a, a^k) * x[n,a] * y[n,a^k]
//
// ROUND 8: overhead A/B experiment. Kernel body is byte-identical to the
// best measured variant (R4, 16.60 us: xor-nibble decomposition, stride-65
// LDS, compile-time signs). Single change: the batch is processed by TWO
// identical dispatches (rows [0,32768) and [32768,65536), 512 blocks each)
// instead of one 1024-block dispatch. Work, traffic, and per-CU residency
// are unchanged -- only launch count doubles. If dur jumps ~+8 us, the
// ~9 us gap between the 16.6 us plateau and the 7.6 us memory floor is
// per-launch overhead and the kernel itself is at roofline.

__host__ __device__ constexpr int popc6(int v) {
  int c = 0;
  for (int i = 0; i < 6; ++i) c += (v >> i) & 1;
  return c;
}

__host__ __device__ constexpr float sign_ab(int a, int b) {
  int sw = 0;
  for (int bit = 0; bit < 6; ++bit)
    if ((a >> bit) & 1) sw += popc6(b & ((1 << bit) - 1));
  float s = (sw & 1) ? -1.0f : 1.0f;
  if (popc6(a & b & 0x18) & 1) s = -s;  // negative dims: bits 3,4
  if (a & b & 0x20) s = 0.0f;           // null dim: bit 5
  return s;
}

template <int Q, int ALO, int AHI, int KK>
__device__ __forceinline__ void term(float xa, const float (&yr)[16], float (&acc)[16]) {
  constexpr int a = 4 * AHI + ALO;
  constexpr int b = 4 * (AHI ^ KK) + (ALO ^ Q);
  constexpr float sg = sign_ab(a, b);
  if constexpr (sg > 0.0f)      acc[KK] = fmaf( xa, yr[AHI ^ KK], acc[KK]);
  else if constexpr (sg < 0.0f) acc[KK] = fmaf(-xa, yr[AHI ^ KK], acc[KK]);
}

template <int Q, int ALO, int AHI, int... KK>
__device__ __forceinline__ void terms(float xa, const float (&yr)[16], float (&acc)[16],
                                      std::integer_sequence<int, KK...>) {
  (term<Q, ALO, AHI, KK>(xa, yr, acc), ...);
}

template <int Q, int ALO, int... AHI>
__device__ __forceinline__ void stream_x(const float* __restrict__ xrow,
                                         const float (&yr)[16], float (&acc)[16],
                                         std::integer_sequence<int, AHI...>) {
  (terms<Q, ALO, AHI>(xrow[4 * AHI + ALO], yr, acc,
                      std::make_integer_sequence<int, 16>{}), ...);
}

template <int Q, int ALO, int... HH>
__device__ __forceinline__ void load_y(const float* __restrict__ yrow, float (&yr)[16],
                                       std::integer_sequence<int, HH...>) {
  ((yr[HH] = yrow[4 * HH + (ALO ^ Q)]), ...);
}

template <int Q, int ALO>
__device__ __forceinline__ void group(const float* __restrict__ xrow,
                                      const float* __restrict__ yrow, float (&acc)[16]) {
  float yr[16];
  load_y<Q, ALO>(yrow, yr, std::make_integer_sequence<int, 16>{});
  stream_x<Q, ALO>(xrow, yr, acc, std::make_integer_sequence<int, 16>{});
}

template <int Q>
__device__ __forceinline__ void compute(const float* __restrict__ xrow,
                                        const float* __restrict__ yrow, float (&acc)[16]) {
  group<Q, 0>(xrow, yrow, acc);
  group<Q, 1>(xrow, yrow, acc);
  group<Q, 2>(xrow, yrow, acc);
  group<Q, 3>(xrow, yrow, acc);
}

__global__ __launch_bounds__(256) void clgp_kernel(const float* __restrict__ xg,
                                                   const float* __restrict__ yg,
                                                   float* __restrict__ og) {
  __shared__ float xl[64 * 65];
  __shared__ float yl[64 * 65];

  const int t = threadIdx.x;
  const long tile = (long)blockIdx.x * 4096;  // 64 rows * 64 cols

  const float4* x4 = (const float4*)(xg + tile);
  const float4* y4 = (const float4*)(yg + tile);
  float4 rx[4], ry[4];
#pragma unroll
  for (int p = 0; p < 4; ++p) {
    rx[p] = x4[t + p * 256];
    ry[p] = y4[t + p * 256];
  }
#pragma unroll
  for (int p = 0; p < 4; ++p) {
    const int v = t + p * 256;
    const int w = (v >> 4) * 65 + (v & 15) * 4;
    xl[w + 0] = rx[p].x; xl[w + 1] = rx[p].y; xl[w + 2] = rx[p].z; xl[w + 3] = rx[p].w;
    yl[w + 0] = ry[p].x; yl[w + 1] = ry[p].y; yl[w + 2] = ry[p].z; yl[w + 3] = ry[p].w;
  }
  __syncthreads();

  const int lane = t & 63;
  const int q = t >> 6;

  float acc[16];
#pragma unroll
  for (int i = 0; i < 16; ++i) acc[i] = 0.0f;

  const float* xrow = &xl[lane * 65];
  const float* yrow = &yl[lane * 65];
  switch (q) {
    case 0:  compute<0>(xrow, yrow, acc); break;
    case 1:  compute<1>(xrow, yrow, acc); break;
    case 2:  compute<2>(xrow, yrow, acc); break;
    default: compute<3>(xrow, yrow, acc); break;
  }

  __syncthreads();
#pragma unroll
  for (int kk = 0; kk < 16; ++kk) xl[lane * 65 + q + 4 * kk] = acc[kk];
  __syncthreads();

  float4* o4 = (float4*)(og + tile);
#pragma unroll
  for (int p = 0; p < 4; ++p) {
    const int v = t + p * 256;
    const int w = (v >> 4) * 65 + (v & 15) * 4;
    float4 o;
    o.x = xl[w + 0]; o.y = xl[w + 1]; o.z = xl[w + 2]; o.w = xl[w + 3];
    o4[v] = o;
  }
}

extern "C" void kernel_launch(void* const* d_in, const int* in_sizes, int n_in,
                              void* d_out, int out_size, void* d_ws, size_t ws_size,
                              hipStream_t stream) {
  const float* x = (const float*)d_in[0];
  const float* y = (const float*)d_in[1];
  float* out = (float*)d_out;
  const int n_batch = in_sizes[0] / 64;       // 65536
  const int half_rows = n_batch / 2;          // 32768
  const int grid = half_rows / 64;            // 512 blocks per launch
  const long off = (long)half_rows * 64;      // element offset of second half
  clgp_kernel<<<grid, 256, 0, stream>>>(x, y, out);
  clgp_kernel<<<grid, 256, 0, stream>>>(x + off, y + off, out + off);
}